// Round 10
// baseline (57.294 us; speedup 1.0000x reference)
//
#include <hip/hip_runtime.h>
#include <math.h>

namespace {
constexpr int kB = 256;
constexpr int kT = 64;
constexpr int kPhys = 3;
constexpr int kLat = 8;
constexpr int kNN = 128;
constexpr int kWin = 32;
constexpr int kPred = 64;
constexpr int kHRow = 132;
constexpr int kWUnit = 8 * 4 * 64 * 8;  // 16384 shorts per weight plane-unit
}

typedef short bf16x8 __attribute__((ext_vector_type(8)));
typedef float f32x4 __attribute__((ext_vector_type(4)));

__device__ __forceinline__ double rdlane_f64(double x, int l) {
  const long long v = __double_as_longlong(x);
  const int lo = __builtin_amdgcn_readlane((int)(unsigned int)(v & 0xffffffffll), l);
  const int hi = __builtin_amdgcn_readlane((int)(v >> 32), l);
  const long long r = (((long long)hi) << 32) | (unsigned long long)(unsigned int)lo;
  return __longlong_as_double(r);
}

__device__ __forceinline__ unsigned rneb(float f) {  // f32 -> bf16 bits (RNE)
  const unsigned u = __float_as_uint(f);
  return (u + 0x7fffu + ((u >> 16) & 1u)) >> 16;
}
__device__ __forceinline__ void split3(float a, short& s1, short& s2, short& s3) {
  const unsigned b1 = rneb(a);
  const float f1 = __uint_as_float(b1 << 16);
  const float r1 = a - f1;
  const unsigned b2 = rneb(r1);
  const float f2 = __uint_as_float(b2 << 16);
  s1 = (short)b1; s2 = (short)b2; s3 = (short)rneb(r1 - f2);
}
__device__ __forceinline__ void split2(float a, short& s1, short& s2) {
  const unsigned b1 = rneb(a);
  const float f1 = __uint_as_float(b1 << 16);
  s1 = (short)b1; s2 = (short)rneb(a - f1);
}

// ---- prologue: split hidden weights into B-fragment planes (launch-invariant) ----
__global__ __launch_bounds__(256) void split_weights_kernel(
    const float* __restrict__ ewh, const float* __restrict__ dwh,
    short* __restrict__ wfrag)
{
  const int gid = blockIdx.x * 256 + threadIdx.x;  // 12288
  const int l = gid & 63;
  const int q = (gid >> 6) & 3;
  const int n = (gid >> 8) & 7;
  const int layer = gid >> 11;  // 0..5
  const bool enc = layer < 3;
  const float* __restrict__ W = enc ? (ewh + (size_t)layer * kNN * kNN)
                                    : (dwh + (size_t)(layer - 3) * kNN * kNN);
  const int colg = 16 * n + (l & 15);
  const int krow = 8 * (l >> 4);
  bf16x8 p1, p2, p3;
#pragma unroll
  for (int e = 0; e < 8; ++e) {
    const float wv = W[(32 * q + krow + e) * kNN + colg];
    short s1, s2, s3; split3(wv, s1, s2, s3);
    p1[e] = s1; p2[e] = s2; p3[e] = s3;
  }
  const int off = ((n * 4 + q) * 64 + l) * 8;
  if (enc) {
    const size_t base = (size_t)(layer * 3) * kWUnit;
    *(bf16x8*)&wfrag[base + off] = p1;
    *(bf16x8*)&wfrag[base + kWUnit + off] = p2;
    *(bf16x8*)&wfrag[base + 2 * kWUnit + off] = p3;
  } else {
    const size_t base = (size_t)(9 + (layer - 3) * 2) * kWUnit;
    *(bf16x8*)&wfrag[base + off] = p1;
    *(bf16x8*)&wfrag[base + kWUnit + off] = p2;
  }
}

// ---- hidden layer for 8-wave block; wave w owns n-tile w, all MT m-tiles ----
template<int MT, int SPLITS, bool TO_FRAG>
__device__ __forceinline__ void mfma_layer8(
    const short* __restrict__ Bfrag, const float* __restrict__ bias,
    const short* __restrict__ fragIn, void* __restrict__ out, int tid)
{
  constexpr int PLANE = MT * 4 * 64 * 8;
  const int n = (tid >> 6) & 7, l = tid & 63;
  const int colg = 16 * n + (l & 15);
  bf16x8 B1[4], B2[4], B3[4];
#pragma unroll
  for (int q = 0; q < 4; ++q) {
    const int boff = ((n * 4 + q) * 64 + l) * 8;
    B1[q] = *(const bf16x8*)&Bfrag[boff];
    B2[q] = *(const bf16x8*)&Bfrag[kWUnit + boff];
    if constexpr (SPLITS == 3) B3[q] = *(const bf16x8*)&Bfrag[2 * kWUnit + boff];
  }
  const float bj = bias[colg];
  f32x4 acc[MT];
#pragma unroll
  for (int mi = 0; mi < MT; ++mi) acc[mi] = {bj, bj, bj, bj};
#pragma unroll
  for (int q = 0; q < 4; ++q) {
#pragma unroll
    for (int mi = 0; mi < MT; ++mi) {
      const int o = ((mi * 4 + q) * 64 + l) * 8;
      const bf16x8 a1 = *(const bf16x8*)&fragIn[o];
      const bf16x8 a2 = *(const bf16x8*)&fragIn[PLANE + o];
      acc[mi] = __builtin_amdgcn_mfma_f32_16x16x32_bf16(a1, B1[q], acc[mi], 0, 0, 0);
      acc[mi] = __builtin_amdgcn_mfma_f32_16x16x32_bf16(a1, B2[q], acc[mi], 0, 0, 0);
      acc[mi] = __builtin_amdgcn_mfma_f32_16x16x32_bf16(a2, B1[q], acc[mi], 0, 0, 0);
      if constexpr (SPLITS == 3) {
        const bf16x8 a3 = *(const bf16x8*)&fragIn[2 * PLANE + o];
        acc[mi] = __builtin_amdgcn_mfma_f32_16x16x32_bf16(a1, B3[q], acc[mi], 0, 0, 0);
        acc[mi] = __builtin_amdgcn_mfma_f32_16x16x32_bf16(a2, B2[q], acc[mi], 0, 0, 0);
        acc[mi] = __builtin_amdgcn_mfma_f32_16x16x32_bf16(a3, B1[q], acc[mi], 0, 0, 0);
      }
    }
  }
  const int rbase = (l >> 4) * 4;
  if constexpr (TO_FRAG) {
    short* __restrict__ f = (short*)out;
    const int qt = colg >> 5, sub = (colg >> 3) & 3, et = colg & 7;
#pragma unroll
    for (int mi = 0; mi < MT; ++mi)
#pragma unroll
      for (int r = 0; r < 4; ++r) {
        const float v = fmaxf(acc[mi][r], 0.f);
        const int off = ((mi * 4 + qt) * 64 + (rbase + r + 16 * sub)) * 8 + et;
        if constexpr (SPLITS == 3) {
          short s1, s2, s3; split3(v, s1, s2, s3);
          f[off] = s1; f[PLANE + off] = s2; f[2 * PLANE + off] = s3;
        } else {
          short s1, s2; split2(v, s1, s2);
          f[off] = s1; f[PLANE + off] = s2;
        }
      }
  } else {
    float* __restrict__ hb = (float*)out;
#pragma unroll
    for (int mi = 0; mi < MT; ++mi)
#pragma unroll
      for (int r = 0; r < 4; ++r)
        hb[(16 * mi + rbase + r) * kHRow + colg] = fmaxf(acc[mi][r], 0.f);
  }
}

// =============== ENCODER: 512 blocks, (batch, 32-row half) ===============
__global__ __launch_bounds__(512, 4) void enc_kernel(
    const float* __restrict__ x,
    const float* __restrict__ ewin, const float* __restrict__ ebin,
    const float* __restrict__ ebh,
    const float* __restrict__ ewout,const float* __restrict__ ebout,
    const short* __restrict__ wfrag, float* __restrict__ y_g)
{
  constexpr int PE = 2 * 4 * 64 * 8;  // 4096 shorts per plane (MT=2)
  __shared__ __align__(16) char US1[24576];
  __shared__ __align__(16) char US2[24576];
  const int tid = threadIdx.x;
  const int b = blockIdx.x >> 1;
  const int r0 = (blockIdx.x & 1) * 32;

  // input layer 3 -> 128, rows [r0, r0+32), scatter-frag into US1
  {
    short* __restrict__ f = (short*)US1;
    const int j = tid & 127, rg = tid >> 7;  // 4 groups x 8 rows
    const float w0 = ewin[j], w1 = ewin[kNN + j], w2 = ewin[2 * kNN + j];
    const float bj = ebin[j];
    const int qt = j >> 5, sub = (j >> 3) & 3, et = j & 7;
#pragma unroll
    for (int rr = 0; rr < 8; ++rr) {
      const int r = rg * 8 + rr;                 // local row 0..31
      const float* __restrict__ xr = x + ((size_t)b * kT + r0 + r) * kPhys;
      const float a = fmaxf(bj + xr[0] * w0 + xr[1] * w1 + xr[2] * w2, 0.f);
      short s1, s2, s3; split3(a, s1, s2, s3);
      const int off = (((r >> 4) * 4 + qt) * 64 + ((r & 15) + 16 * sub)) * 8 + et;
      f[off] = s1; f[PE + off] = s2; f[2 * PE + off] = s3;
    }
  }
  __syncthreads();
  mfma_layer8<2, 3, true >(wfrag + (size_t)0 * kWUnit, ebh + 0 * kNN, (short*)US1, US2, tid);
  __syncthreads();
  mfma_layer8<2, 3, true >(wfrag + (size_t)3 * kWUnit, ebh + 1 * kNN, (short*)US2, US1, tid);
  __syncthreads();
  mfma_layer8<2, 3, false>(wfrag + (size_t)6 * kWUnit, ebh + 2 * kNN, (short*)US1, US2, tid);
  __syncthreads();

  // output layer 128 -> 8
  if (tid < 256) {
    const float* __restrict__ hb = (const float*)US2;
    const int r = tid >> 3, o = tid & 7;
    float a = ebout[o];
    for (int k4 = 0; k4 < kNN; k4 += 4) {
      const float4 hv = *(const float4*)&hb[r * kHRow + k4];
      a += hv.x * ewout[(k4 + 0) * kLat + o] + hv.y * ewout[(k4 + 1) * kLat + o]
         + hv.z * ewout[(k4 + 2) * kLat + o] + hv.w * ewout[(k4 + 3) * kLat + o];
    }
    y_g[(size_t)b * kT * kLat + (r0 + r) * kLat + o] = a;
  }
}

// =============== DMD: 256 blocks (1 per batch), f64 exact-math ===============
__global__ __launch_bounds__(512) void dmd_kernel(const float* __restrict__ y_g,
                                                  float* __restrict__ yadv_g)
{
  __shared__ __align__(16) char US[46400];
  double* dmd  = (double*)US;
  double* yd   = dmd;           // [8][65]
  double* P    = dmd + 520;     // [32][67]
  double* Corr = dmd + 2664;    // [32][33]
  double* KTm  = dmd + 3720;    // [31][33]
  double* Dv   = dmd + 4743;    // [32][33]
  const int tid = threadIdx.x;
  const int b = blockIdx.x;
  const float* __restrict__ yb = y_g + (size_t)b * kT * kLat;

  {
    const int r = tid >> 3, o = tid & 7;  // 512 = 64*8
    yd[o * 65 + r] = (double)yb[tid];
  }
  __syncthreads();

  for (int idx = tid; idx < 32 * 64; idx += 512) {
    const int d = idx >> 6, t = idx & 63;
    if (t + d < kT) {
      double s = 0.0;
#pragma unroll
      for (int l = 0; l < kLat; ++l) s += yd[l * 65 + t] * yd[l * 65 + t + d];
      P[d * 67 + t] = s;
    }
  }
  __syncthreads();

  for (int idx = tid; idx < 32 * 32; idx += 512) {
    const int a = idx >> 5, c = idx & 31;
    const int d = (c >= a) ? (c - a) : (a - c);
    const int base = (c >= a) ? a : c;
    double s0 = 0.0, s1 = 0.0;
#pragma unroll
    for (int r = 0; r < 32; r += 2) { s0 += P[d * 67 + base + r]; s1 += P[d * 67 + base + r + 1]; }
    Corr[a * 33 + c] = s0 + s1 + P[d * 67 + base + 32];
  }
  __syncthreads();

  if (tid < 64) {
    const int lane = tid;
    const int colidx = (lane <= 30) ? lane : (lane <= 61 ? lane - 30 : 1);
    double m[31];
#pragma unroll
    for (int i = 0; i < 31; ++i) m[i] = Corr[i * 33 + colidx];
#pragma unroll
    for (int k = 0; k < 31; ++k) {
      const double piv = rdlane_f64(m[k], k);
      const double pinv = 1.0 / piv;
      m[k] *= pinv;
#pragma unroll
      for (int i = 0; i < 31; ++i) {
        if (i == k) continue;
        const double bci = rdlane_f64(m[i], k);
        m[i] = fma(-bci, m[k], m[i]);
      }
    }
    if (lane >= 31 && lane < 62) {
      const int c = lane - 31;
#pragma unroll
      for (int i = 0; i < 31; ++i) KTm[i * 33 + c] = m[i];
    }
    const int ri = (lane < 31) ? lane : 0;
    double Kr[31];
#pragma unroll
    for (int j = 0; j < 31; ++j) Kr[j] = KTm[ri * 33 + j];

    double dv = Kr[30];  // d_0 = K[:,30]
    if (lane < 31) Dv[0 * 33 + lane] = dv;
    for (int k = 0; k < 31; ++k) {
      double a0 = 0.0, a1 = 0.0, a2 = 0.0, a3 = 0.0;
#pragma unroll
      for (int j = 0; j < 31; ++j) {
        const double dj = rdlane_f64(dv, j);
        if ((j & 3) == 0) a0 = fma(Kr[j], dj, a0);
        else if ((j & 3) == 1) a1 = fma(Kr[j], dj, a1);
        else if ((j & 3) == 2) a2 = fma(Kr[j], dj, a2);
        else a3 = fma(Kr[j], dj, a3);
      }
      dv = (a0 + a1) + (a2 + a3);
      if (lane < 31) Dv[(k + 1) * 33 + lane] = dv;
    }
  }
  __syncthreads();

  float* __restrict__ ob = yadv_g + (size_t)b * kPred * kLat;
  if (tid < 256) {
    ob[tid] = yb[tid];  // p < 32: exact copy of y
  } else {
    const int q = tid - 256;
    const int k = q >> 3, l = q & 7;
    double a0 = 0.0, a1 = 0.0, a2 = 0.0, a3 = 0.0;
#pragma unroll
    for (int j = 0; j < 31; ++j) {
      const double t = yd[l * 65 + j + 1];
      if ((j & 3) == 0) a0 = fma(t, Dv[k * 33 + j], a0);
      else if ((j & 3) == 1) a1 = fma(t, Dv[k * 33 + j], a1);
      else if ((j & 3) == 2) a2 = fma(t, Dv[k * 33 + j], a2);
      else a3 = fma(t, Dv[k * 33 + j], a3);
    }
    ob[256 + q] = (float)((a0 + a1) + (a2 + a3));
  }
}

// =============== DECODER: 512 blocks, (batch, 48-row half) ===============
__global__ __launch_bounds__(512, 4) void dec_kernel(
    const float* __restrict__ y_g, const float* __restrict__ yadv_g,
    const float* __restrict__ dwin, const float* __restrict__ dbin,
    const float* __restrict__ dbh,
    const float* __restrict__ dwout,const float* __restrict__ dbout,
    const short* __restrict__ wfrag,
    float* __restrict__ xae_g, float* __restrict__ xadv_g)
{
  constexpr int PD = 3 * 4 * 64 * 8;  // 6144 shorts per plane (MT=3)
  __shared__ __align__(16) char US1[25344];
  __shared__ __align__(16) char US2[25344];
  __shared__ float src48[48 * kLat];
  const int tid = threadIdx.x;
  const int b = blockIdx.x >> 1;
  const int R0 = (blockIdx.x & 1) * 48;

  // stage input rows [R0, R0+48): gr<64 -> y, else yadv row gr-32
  for (int i = tid; i < 48 * kLat; i += 512) {
    const int r = i >> 3, o = i & 7;
    const int gr = R0 + r;
    src48[i] = (gr < kT) ? y_g[(size_t)b * kT * kLat + gr * kLat + o]
                         : yadv_g[(size_t)b * kPred * kLat + (gr - kWin) * kLat + o];
  }
  __syncthreads();

  // input layer 8 -> 128, scatter-frag into US1 (2-split)
  {
    short* __restrict__ f = (short*)US1;
    const int j = tid & 127, rg = tid >> 7;  // 4 groups x 12 rows
    float wr[kLat];
#pragma unroll
    for (int k = 0; k < kLat; ++k) wr[k] = dwin[k * kNN + j];
    const float bj = dbin[j];
    const int qt = j >> 5, sub = (j >> 3) & 3, et = j & 7;
#pragma unroll
    for (int rr = 0; rr < 12; ++rr) {
      const int r = rg * 12 + rr;  // local 0..47
      const float* __restrict__ src = &src48[r * kLat];
      float a = bj;
#pragma unroll
      for (int k = 0; k < kLat; ++k) a += src[k] * wr[k];
      a = fmaxf(a, 0.f);
      short s1, s2; split2(a, s1, s2);
      const int off = (((r >> 4) * 4 + qt) * 64 + ((r & 15) + 16 * sub)) * 8 + et;
      f[off] = s1; f[PD + off] = s2;
    }
  }
  __syncthreads();
  mfma_layer8<3, 2, true >(wfrag + (size_t)9  * kWUnit, dbh + 0 * kNN, (short*)US1, US2, tid);
  __syncthreads();
  mfma_layer8<3, 2, true >(wfrag + (size_t)11 * kWUnit, dbh + 1 * kNN, (short*)US2, US1, tid);
  __syncthreads();
  mfma_layer8<3, 2, false>(wfrag + (size_t)13 * kWUnit, dbh + 2 * kNN, (short*)US1, US2, tid);
  __syncthreads();

  // output layer 128 -> 3
  if (tid < 48 * kPhys) {
    const float* __restrict__ hb = (const float*)US2;
    const int r = tid / 3, o = tid - r * 3;
    const int gr = R0 + r;
    float a = dbout[o];
    for (int k4 = 0; k4 < kNN; k4 += 4) {
      const float4 hv = *(const float4*)&hb[r * kHRow + k4];
      a += hv.x * dwout[(k4 + 0) * kPhys + o] + hv.y * dwout[(k4 + 1) * kPhys + o]
         + hv.z * dwout[(k4 + 2) * kPhys + o] + hv.w * dwout[(k4 + 3) * kPhys + o];
    }
    if (gr < kT) {
      xae_g[(size_t)b * kT * kPhys + gr * kPhys + o] = a;
      if (gr < kWin) xadv_g[(size_t)b * kT * kPhys + gr * kPhys + o] = a;
    } else {
      const int rr = gr - kT + kWin;  // 32..63
      xadv_g[(size_t)b * kT * kPhys + rr * kPhys + o] = a;
    }
  }
}

extern "C" void kernel_launch(void* const* d_in, const int* in_sizes, int n_in,
                              void* d_out, int out_size, void* d_ws, size_t ws_size,
                              hipStream_t stream)
{
  const float* x         = (const float*)d_in[0];
  const float* enc_w_in  = (const float*)d_in[1];
  const float* enc_b_in  = (const float*)d_in[2];
  const float* enc_w_h   = (const float*)d_in[3];
  const float* enc_b_h   = (const float*)d_in[4];
  const float* enc_w_out = (const float*)d_in[5];
  const float* enc_b_out = (const float*)d_in[6];
  const float* dec_w_in  = (const float*)d_in[7];
  const float* dec_b_in  = (const float*)d_in[8];
  const float* dec_w_h   = (const float*)d_in[9];
  const float* dec_b_h   = (const float*)d_in[10];
  const float* dec_w_out = (const float*)d_in[11];
  const float* dec_b_out = (const float*)d_in[12];

  float* out   = (float*)d_out;
  float* y     = out;                                  // (B,T,8)   131072
  float* x_ae  = out + (size_t)kB * kT * kLat;         // (B,T,3)    49152
  float* x_adv = x_ae + (size_t)kB * kT * kPhys;       // (B,T,3)    49152
  float* y_adv = x_adv + (size_t)kB * kT * kPhys;      // (B,64,8)  131072

  short* wfrag = (short*)d_ws;   // 15 units x 16384 shorts = 491520 B

  split_weights_kernel<<<48, 256, 0, stream>>>(enc_w_h, dec_w_h, wfrag);
  enc_kernel<<<2 * kB, 512, 0, stream>>>(
      x, enc_w_in, enc_b_in, enc_b_h, enc_w_out, enc_b_out, wfrag, y);
  dmd_kernel<<<kB, 512, 0, stream>>>(y, y_adv);
  dec_kernel<<<2 * kB, 512, 0, stream>>>(
      y, y_adv, dec_w_in, dec_b_in, dec_b_h, dec_w_out, dec_b_out,
      wfrag, x_ae, x_adv);
}

// Round 11
// 55.375 us; speedup vs baseline: 1.0346x; 1.0346x over previous
//
#include <hip/hip_runtime.h>
#include <math.h>

namespace {
constexpr int kB = 256;
constexpr int kT = 64;
constexpr int kPhys = 3;
constexpr int kLat = 8;
constexpr int kNN = 128;
constexpr int kWin = 32;
constexpr int kPred = 64;
constexpr int kHRow = 132;
constexpr int kThreads = 1024;
constexpr int kWUnit = 8 * 4 * 64 * 8;  // 16384 shorts per weight plane-unit
}

typedef short bf16x8 __attribute__((ext_vector_type(8)));
typedef float f32x4 __attribute__((ext_vector_type(4)));

__device__ __forceinline__ double rdlane_f64(double x, int l) {
  const long long v = __double_as_longlong(x);
  const int lo = __builtin_amdgcn_readlane((int)(unsigned int)(v & 0xffffffffll), l);
  const int hi = __builtin_amdgcn_readlane((int)(v >> 32), l);
  const long long r = (((long long)hi) << 32) | (unsigned long long)(unsigned int)lo;
  return __longlong_as_double(r);
}

__device__ __forceinline__ unsigned rneb(float f) {  // f32 -> bf16 bits (RNE)
  const unsigned u = __float_as_uint(f);
  return (u + 0x7fffu + ((u >> 16) & 1u)) >> 16;
}
__device__ __forceinline__ void split3(float a, short& s1, short& s2, short& s3) {
  const unsigned b1 = rneb(a);
  const float f1 = __uint_as_float(b1 << 16);
  const float r1 = a - f1;
  const unsigned b2 = rneb(r1);
  const float f2 = __uint_as_float(b2 << 16);
  s1 = (short)b1; s2 = (short)b2; s3 = (short)rneb(r1 - f2);
}
__device__ __forceinline__ void split2(float a, short& s1, short& s2) {
  const unsigned b1 = rneb(a);
  const float f1 = __uint_as_float(b1 << 16);
  s1 = (short)b1; s2 = (short)rneb(a - f1);
}

// ---- prologue: split hidden weights into B-fragment planes (launch-invariant) ----
__global__ __launch_bounds__(256) void split_weights_kernel(
    const float* __restrict__ ewh, const float* __restrict__ dwh,
    short* __restrict__ wfrag)
{
  const int gid = blockIdx.x * 256 + threadIdx.x;  // 12288
  const int l = gid & 63;
  const int q = (gid >> 6) & 3;
  const int n = (gid >> 8) & 7;
  const int layer = gid >> 11;  // 0..5
  const bool enc = layer < 3;
  const float* __restrict__ W = enc ? (ewh + (size_t)layer * kNN * kNN)
                                    : (dwh + (size_t)(layer - 3) * kNN * kNN);
  const int colg = 16 * n + (l & 15);
  const int krow = 8 * (l >> 4);
  bf16x8 p1, p2, p3;
#pragma unroll
  for (int e = 0; e < 8; ++e) {
    const float wv = W[(32 * q + krow + e) * kNN + colg];
    short s1, s2, s3; split3(wv, s1, s2, s3);
    p1[e] = s1; p2[e] = s2; p3[e] = s3;
  }
  const int off = ((n * 4 + q) * 64 + l) * 8;
  if (enc) {
    const size_t base = (size_t)(layer * 3) * kWUnit;
    *(bf16x8*)&wfrag[base + off] = p1;
    *(bf16x8*)&wfrag[base + kWUnit + off] = p2;
    *(bf16x8*)&wfrag[base + 2 * kWUnit + off] = p3;
  } else {
    const size_t base = (size_t)(9 + (layer - 3) * 2) * kWUnit;
    *(bf16x8*)&wfrag[base + off] = p1;
    *(bf16x8*)&wfrag[base + kWUnit + off] = p2;
  }
}

// ---- encoder hidden layer (16 waves: n = w&7, m-group = w>>3) ----
template<int MPW, int SPLITS, bool TO_FRAG>
__device__ __forceinline__ void mfma_enc(
    const short* __restrict__ Bfrag, const float* __restrict__ bias,
    const short* __restrict__ fragIn, void* __restrict__ out, int tid)
{
  constexpr int MT = 2 * MPW;
  constexpr int PLANE = MT * 4 * 64 * 8;
  const int w = tid >> 6, l = tid & 63;
  const int n = w & 7, m0 = (w >> 3) * MPW;
  const int colg = 16 * n + (l & 15);
  bf16x8 B1[4], B2[4], B3[4];
#pragma unroll
  for (int q = 0; q < 4; ++q) {
    const int boff = ((n * 4 + q) * 64 + l) * 8;
    B1[q] = *(const bf16x8*)&Bfrag[boff];
    B2[q] = *(const bf16x8*)&Bfrag[kWUnit + boff];
    if constexpr (SPLITS == 3) B3[q] = *(const bf16x8*)&Bfrag[2 * kWUnit + boff];
  }
  const float bj = bias[colg];
  f32x4 acc[MPW];
#pragma unroll
  for (int mi = 0; mi < MPW; ++mi) acc[mi] = {bj, bj, bj, bj};
#pragma unroll
  for (int q = 0; q < 4; ++q) {
#pragma unroll
    for (int mi = 0; mi < MPW; ++mi) {
      const int o = (((m0 + mi) * 4 + q) * 64 + l) * 8;
      const bf16x8 a1 = *(const bf16x8*)&fragIn[o];
      const bf16x8 a2 = *(const bf16x8*)&fragIn[PLANE + o];
      acc[mi] = __builtin_amdgcn_mfma_f32_16x16x32_bf16(a1, B1[q], acc[mi], 0, 0, 0);
      acc[mi] = __builtin_amdgcn_mfma_f32_16x16x32_bf16(a1, B2[q], acc[mi], 0, 0, 0);
      acc[mi] = __builtin_amdgcn_mfma_f32_16x16x32_bf16(a2, B1[q], acc[mi], 0, 0, 0);
      if constexpr (SPLITS == 3) {
        const bf16x8 a3 = *(const bf16x8*)&fragIn[2 * PLANE + o];
        acc[mi] = __builtin_amdgcn_mfma_f32_16x16x32_bf16(a1, B3[q], acc[mi], 0, 0, 0);
        acc[mi] = __builtin_amdgcn_mfma_f32_16x16x32_bf16(a2, B2[q], acc[mi], 0, 0, 0);
        acc[mi] = __builtin_amdgcn_mfma_f32_16x16x32_bf16(a3, B1[q], acc[mi], 0, 0, 0);
      }
    }
  }
  const int rbase = (l >> 4) * 4;
  if constexpr (TO_FRAG) {
    short* __restrict__ f = (short*)out;
    const int qt = colg >> 5, sub = (colg >> 3) & 3, et = colg & 7;
#pragma unroll
    for (int mi = 0; mi < MPW; ++mi)
#pragma unroll
      for (int r = 0; r < 4; ++r) {
        const float v = fmaxf(acc[mi][r], 0.f);
        const int off = (((m0 + mi) * 4 + qt) * 64 + (rbase + r + 16 * sub)) * 8 + et;
        short s1, s2, s3; split3(v, s1, s2, s3);
        f[off] = s1; f[PLANE + off] = s2; f[2 * PLANE + off] = s3;
      }
  } else {
    float* __restrict__ hb = (float*)out;
#pragma unroll
    for (int mi = 0; mi < MPW; ++mi)
#pragma unroll
      for (int r = 0; r < 4; ++r)
        hb[(16 * (m0 + mi) + rbase + r) * kHRow + colg] = fmaxf(acc[mi][r], 0.f);
  }
}

// ---- decoder tile-set layer (8 waves; wave handles all MTN m-tiles, 2-split) ----
template<int MTN, bool TO_FRAG>
__device__ __forceinline__ void mfma_dec(
    const short* __restrict__ Bfrag, const float* __restrict__ bias,
    const short* __restrict__ fragIn, void* __restrict__ out, int n, int l)
{
  constexpr int PLANE = MTN * 4 * 64 * 8;
  const int colg = 16 * n + (l & 15);
  bf16x8 B1[4], B2[4];
#pragma unroll
  for (int q = 0; q < 4; ++q) {
    const int boff = ((n * 4 + q) * 64 + l) * 8;
    B1[q] = *(const bf16x8*)&Bfrag[boff];
    B2[q] = *(const bf16x8*)&Bfrag[kWUnit + boff];
  }
  const float bj = bias[colg];
  f32x4 acc[MTN];
#pragma unroll
  for (int mi = 0; mi < MTN; ++mi) acc[mi] = {bj, bj, bj, bj};
#pragma unroll
  for (int q = 0; q < 4; ++q) {
#pragma unroll
    for (int mi = 0; mi < MTN; ++mi) {
      const int o = ((mi * 4 + q) * 64 + l) * 8;
      const bf16x8 a1 = *(const bf16x8*)&fragIn[o];
      const bf16x8 a2 = *(const bf16x8*)&fragIn[PLANE + o];
      acc[mi] = __builtin_amdgcn_mfma_f32_16x16x32_bf16(a1, B1[q], acc[mi], 0, 0, 0);
      acc[mi] = __builtin_amdgcn_mfma_f32_16x16x32_bf16(a1, B2[q], acc[mi], 0, 0, 0);
      acc[mi] = __builtin_amdgcn_mfma_f32_16x16x32_bf16(a2, B1[q], acc[mi], 0, 0, 0);
    }
  }
  const int rbase = (l >> 4) * 4;
  if constexpr (TO_FRAG) {
    short* __restrict__ f = (short*)out;
    const int qt = colg >> 5, sub = (colg >> 3) & 3, et = colg & 7;
#pragma unroll
    for (int mi = 0; mi < MTN; ++mi)
#pragma unroll
      for (int r = 0; r < 4; ++r) {
        const float v = fmaxf(acc[mi][r], 0.f);
        const int off = ((mi * 4 + qt) * 64 + (rbase + r + 16 * sub)) * 8 + et;
        short s1, s2; split2(v, s1, s2);
        f[off] = s1; f[PLANE + off] = s2;
      }
  } else {
    float* __restrict__ hb = (float*)out;
#pragma unroll
    for (int mi = 0; mi < MTN; ++mi)
#pragma unroll
      for (int r = 0; r < 4; ++r)
        hb[(16 * mi + rbase + r) * kHRow + colg] = fmaxf(acc[mi][r], 0.f);
  }
}

__global__ __launch_bounds__(kThreads, 4) void fused_kernel(
    const float* __restrict__ x,
    const float* __restrict__ ewin, const float* __restrict__ ebin,
    const float* __restrict__ ebh,
    const float* __restrict__ ewout,const float* __restrict__ ebout,
    const float* __restrict__ dwin, const float* __restrict__ dbin,
    const float* __restrict__ dbh,
    const float* __restrict__ dwout,const float* __restrict__ dbout,
    const short* __restrict__ wfrag,
    float* __restrict__ y_g, float* __restrict__ xae_g,
    float* __restrict__ xadv_g, float* __restrict__ yadv_g)
{
  __shared__ __align__(16) char bufA[50688];
  __shared__ __align__(16) char bufB[50688];
  __shared__ __align__(16) double dmdS[5280];
  __shared__ float ybuf[512];
  __shared__ float yadv2[256];
  __shared__ float xstash[192];

  double* P    = dmdS;          // [32][67]  -> 2144
  double* Corr = dmdS + 2144;   // [32][33]  -> 1056
  double* KTm  = dmdS + 3200;   // [31][33]  -> 1023
  double* Dv   = dmdS + 4223;   // [32][33]  -> 1056

  short* fragA_G1 = (short*)bufA;               // 32768 B (dec G1 frag, 2 planes)
  short* fragA_G2 = (short*)(bufA + 32768);     // 16384 B (dec G2 frag, 2 planes)
  short* fragB_G1 = (short*)bufB;
  short* fragB_G2 = (short*)(bufB + 33792);     // after hbB G1 region
  float* hbB_G1   = (float*)bufB;               // [64][132] f32 = 33792 B
  float* hbA_G2   = (float*)bufA;               // [32][132] f32 = 16896 B

  const int tid = threadIdx.x;
  const int l64 = tid & 63;
  const int b = blockIdx.x;

  // ======== ph1: encoder input layer 3 -> 128, scatter-frag into bufA ========
  {
    constexpr int PE = 4 * 4 * 64 * 8;
    short* __restrict__ f = (short*)bufA;
    const float* __restrict__ xg = x + (size_t)b * kT * kPhys;
    const int j = tid & 127, rg = tid >> 7;  // 8 groups x 8 rows
    const float w0 = ewin[j], w1 = ewin[kNN + j], w2 = ewin[2 * kNN + j];
    const float bj = ebin[j];
    const int qt = j >> 5, sub = (j >> 3) & 3, et = j & 7;
#pragma unroll
    for (int rr = 0; rr < 8; ++rr) {
      const int r = rg * 8 + rr;
      const float* __restrict__ xr = xg + r * 3;
      const float a = fmaxf(bj + xr[0] * w0 + xr[1] * w1 + xr[2] * w2, 0.f);
      short s1, s2, s3; split3(a, s1, s2, s3);
      const int off = (((r >> 4) * 4 + qt) * 64 + ((r & 15) + 16 * sub)) * 8 + et;
      f[off] = s1; f[PE + off] = s2; f[2 * PE + off] = s3;
    }
  }
  __syncthreads();

  // ======== ph2-4: encoder hidden layers (3-split, f32-exact) ========
  mfma_enc<2, 3, true >(wfrag + (size_t)0 * kWUnit, ebh + 0 * kNN, (short*)bufA, bufB, tid);
  __syncthreads();
  mfma_enc<2, 3, true >(wfrag + (size_t)3 * kWUnit, ebh + 1 * kNN, (short*)bufB, bufA, tid);
  __syncthreads();
  mfma_enc<2, 3, false>(wfrag + (size_t)6 * kWUnit, ebh + 2 * kNN, (short*)bufA, bufB, tid);
  __syncthreads();

  // ======== ph5: encoder output layer 128 -> 8 -> ybuf (no global store) ========
  if (tid < 512) {
    const float* __restrict__ hb = (const float*)bufB;
    const int r = tid >> 3, o = tid & 7;
    float a = ebout[o];
    for (int k4 = 0; k4 < kNN; k4 += 4) {
      const float4 hv = *(const float4*)&hb[r * kHRow + k4];
      a += hv.x * ewout[(k4 + 0) * kLat + o] + hv.y * ewout[(k4 + 1) * kLat + o]
         + hv.z * ewout[(k4 + 2) * kLat + o] + hv.w * ewout[(k4 + 3) * kLat + o];
    }
    ybuf[tid] = a;
  }
  __syncthreads();

  // ======== ph6: P (tid<512) || dec input scatter rows 0..63 (tid>=512) ========
  if (tid < 512) {
    for (int idx = tid; idx < 32 * 64; idx += 512) {
      const int d = idx >> 6, t = idx & 63;
      if (t + d < kT) {
        double s = 0.0;
#pragma unroll
        for (int l = 0; l < kLat; ++l)
          s += (double)ybuf[t * 8 + l] * (double)ybuf[(t + d) * 8 + l];
        P[d * 67 + t] = s;
      }
    }
  } else {
    constexpr int PD = 4 * 4 * 64 * 8;
    short* __restrict__ f = fragA_G1;
    const int j = tid & 127, rg = (tid >> 7) - 4;  // 4 groups x 16 rows
    float wr[kLat];
#pragma unroll
    for (int k = 0; k < kLat; ++k) wr[k] = dwin[k * kNN + j];
    const float bj = dbin[j];
    const int qt = j >> 5, sub = (j >> 3) & 3, et = j & 7;
#pragma unroll
    for (int rr = 0; rr < 16; ++rr) {
      const int r = rg * 16 + rr;  // 0..63
      const float* __restrict__ src = &ybuf[r * kLat];
      float a = bj;
#pragma unroll
      for (int k = 0; k < kLat; ++k) a += src[k] * wr[k];
      a = fmaxf(a, 0.f);
      short s1, s2; split2(a, s1, s2);
      const int off = (((r >> 4) * 4 + qt) * 64 + ((r & 15) + 16 * sub)) * 8 + et;
      f[off] = s1; f[PD + off] = s2;
    }
  }
  __syncthreads();

  // ======== ph7: Corr ========
  {
    const int a = tid >> 5, c = tid & 31;
    const int d = (c >= a) ? (c - a) : (a - c);
    const int base = (c >= a) ? a : c;
    double s0 = 0.0, s1 = 0.0;
#pragma unroll
    for (int r = 0; r < 32; r += 2) { s0 += P[d * 67 + base + r]; s1 += P[d * 67 + base + r + 1]; }
    Corr[a * 33 + c] = s0 + s1 + P[d * 67 + base + 32];
  }
  __syncthreads();

  // ======== ph8: GJ+power (wave 0) || dec L0 G1 (waves 8..15) ========
  if (tid < 64) {
    const int lane = tid;
    const int colidx = (lane <= 30) ? lane : (lane <= 61 ? lane - 30 : 1);
    double m[31];
#pragma unroll
    for (int i = 0; i < 31; ++i) m[i] = Corr[i * 33 + colidx];
#pragma unroll
    for (int k = 0; k < 31; ++k) {
      const double piv = rdlane_f64(m[k], k);
      const double pinv = 1.0 / piv;
      m[k] *= pinv;
#pragma unroll
      for (int i = 0; i < 31; ++i) {
        if (i == k) continue;
        const double bci = rdlane_f64(m[i], k);
        m[i] = fma(-bci, m[k], m[i]);
      }
    }
    if (lane >= 31 && lane < 62) {
      const int c = lane - 31;
#pragma unroll
      for (int i = 0; i < 31; ++i) KTm[i * 33 + c] = m[i];
    }
    const int ri = (lane < 31) ? lane : 0;
    double Kr[31];
#pragma unroll
    for (int j = 0; j < 31; ++j) Kr[j] = KTm[ri * 33 + j];
    double dv = Kr[30];  // d_0 = K[:,30]
    if (lane < 31) Dv[0 * 33 + lane] = dv;
    for (int k = 0; k < 31; ++k) {
      double a0 = 0.0, a1 = 0.0, a2 = 0.0, a3 = 0.0;
#pragma unroll
      for (int j = 0; j < 31; ++j) {
        const double dj = rdlane_f64(dv, j);
        if ((j & 3) == 0) a0 = fma(Kr[j], dj, a0);
        else if ((j & 3) == 1) a1 = fma(Kr[j], dj, a1);
        else if ((j & 3) == 2) a2 = fma(Kr[j], dj, a2);
        else a3 = fma(Kr[j], dj, a3);
      }
      dv = (a0 + a1) + (a2 + a3);
      if (lane < 31) Dv[(k + 1) * 33 + lane] = dv;
    }
  } else if (tid >= 512) {
    mfma_dec<4, true>(wfrag + (size_t)9 * kWUnit, dbh + 0 * kNN,
                      fragA_G1, fragB_G1, (tid >> 6) - 8, l64);
  }
  __syncthreads();

  // ======== ph9: yadv2 (tid 512..767) || dec L1 G1 (waves 0..7) ========
  if (tid < 512) {
    mfma_dec<4, true>(wfrag + (size_t)11 * kWUnit, dbh + 1 * kNN,
                      fragB_G1, fragA_G1, tid >> 6, l64);
  } else if (tid < 768) {
    const int q = tid - 512;
    const int k = q >> 3, l = q & 7;
    double a0 = 0.0, a1 = 0.0, a2 = 0.0, a3 = 0.0;
#pragma unroll
    for (int j = 0; j < 31; ++j) {
      const double t = (double)ybuf[(j + 1) * 8 + l];
      if ((j & 3) == 0) a0 = fma(t, Dv[k * 33 + j], a0);
      else if ((j & 3) == 1) a1 = fma(t, Dv[k * 33 + j], a1);
      else if ((j & 3) == 2) a2 = fma(t, Dv[k * 33 + j], a2);
      else a3 = fma(t, Dv[k * 33 + j], a3);
    }
    yadv2[q] = (float)((a0 + a1) + (a2 + a3));
  }
  __syncthreads();

  // ======== ph10: dec scatter rows 64..95 (tid>=512) || dec L2 G1 (waves 0..7) ========
  if (tid < 512) {
    mfma_dec<4, false>(wfrag + (size_t)13 * kWUnit, dbh + 2 * kNN,
                       fragA_G1, hbB_G1, tid >> 6, l64);
  } else {
    constexpr int PD = 2 * 4 * 64 * 8;
    short* __restrict__ f = fragA_G2;
    const int j = tid & 127, rg = (tid >> 7) - 4;  // 4 groups x 8 rows
    float wr[kLat];
#pragma unroll
    for (int k = 0; k < kLat; ++k) wr[k] = dwin[k * kNN + j];
    const float bj = dbin[j];
    const int qt = j >> 5, sub = (j >> 3) & 3, et = j & 7;
#pragma unroll
    for (int rr = 0; rr < 8; ++rr) {
      const int r = 64 + rg * 8 + rr;  // 64..95
      const float* __restrict__ src = &yadv2[(r - kT) * kLat];
      float a = bj;
#pragma unroll
      for (int k = 0; k < kLat; ++k) a += src[k] * wr[k];
      a = fmaxf(a, 0.f);
      short s1, s2; split2(a, s1, s2);
      const int mi = (r - 64) >> 4;
      const int off = ((mi * 4 + qt) * 64 + ((r & 15) + 16 * sub)) * 8 + et;
      f[off] = s1; f[PD + off] = s2;
    }
  }
  __syncthreads();

  // ======== ph11: dec out G1 -> xstash (tid<192) || dec L0 G2 (waves 8..15) ========
  if (tid < 192) {
    const int r = tid / 3, o = tid - r * 3;
    float a = dbout[o];
    for (int k4 = 0; k4 < kNN; k4 += 4) {
      const float4 hv = *(const float4*)&hbB_G1[r * kHRow + k4];
      a += hv.x * dwout[(k4 + 0) * kPhys + o] + hv.y * dwout[(k4 + 1) * kPhys + o]
         + hv.z * dwout[(k4 + 2) * kPhys + o] + hv.w * dwout[(k4 + 3) * kPhys + o];
    }
    xstash[tid] = a;
  } else if (tid >= 512) {
    mfma_dec<2, true>(wfrag + (size_t)9 * kWUnit, dbh + 0 * kNN,
                      fragA_G2, fragB_G2, (tid >> 6) - 8, l64);
  }
  __syncthreads();

  // ======== ph12: dec L1 G2 (waves 8..15) ========
  if (tid >= 512) {
    mfma_dec<2, true>(wfrag + (size_t)11 * kWUnit, dbh + 1 * kNN,
                      fragB_G2, fragA_G2, (tid >> 6) - 8, l64);
  }
  __syncthreads();

  // ======== ph13: dec L2 G2 -> hbA (waves 0..7) ========
  if (tid < 512) {
    mfma_dec<2, false>(wfrag + (size_t)13 * kWUnit, dbh + 2 * kNN,
                       fragA_G2, hbA_G2, tid >> 6, l64);
  }
  __syncthreads();

  // ======== ph14 (final, no barrier): G2 out + all global stores ========
  if (tid < 96) {
    const int r = tid / 3, o = tid - r * 3;  // local row 0..31 (global 64+r)
    float a = dbout[o];
    for (int k4 = 0; k4 < kNN; k4 += 4) {
      const float4 hv = *(const float4*)&hbA_G2[r * kHRow + k4];
      a += hv.x * dwout[(k4 + 0) * kPhys + o] + hv.y * dwout[(k4 + 1) * kPhys + o]
         + hv.z * dwout[(k4 + 2) * kPhys + o] + hv.w * dwout[(k4 + 3) * kPhys + o];
    }
    xadv_g[(size_t)b * kT * kPhys + (r + 32) * kPhys + o] = a;
  } else {
    for (int i = tid - 96; i < 192 + 512 + 512; i += kThreads - 96) {
      if (i < 192) {
        xae_g[(size_t)b * kT * kPhys + i] = xstash[i];
        if (i < 96) xadv_g[(size_t)b * kT * kPhys + i] = xstash[i];
      } else if (i < 704) {
        const int q = i - 192;
        yadv_g[(size_t)b * kPred * kLat + q] = (q < 256) ? ybuf[q] : yadv2[q - 256];
      } else {
        const int q = i - 704;
        y_g[(size_t)b * kT * kLat + q] = ybuf[q];
      }
    }
  }
}

extern "C" void kernel_launch(void* const* d_in, const int* in_sizes, int n_in,
                              void* d_out, int out_size, void* d_ws, size_t ws_size,
                              hipStream_t stream)
{
  const float* x         = (const float*)d_in[0];
  const float* enc_w_in  = (const float*)d_in[1];
  const float* enc_b_in  = (const float*)d_in[2];
  const float* enc_w_h   = (const float*)d_in[3];
  const float* enc_b_h   = (const float*)d_in[4];
  const float* enc_w_out = (const float*)d_in[5];
  const float* enc_b_out = (const float*)d_in[6];
  const float* dec_w_in  = (const float*)d_in[7];
  const float* dec_b_in  = (const float*)d_in[8];
  const float* dec_w_h   = (const float*)d_in[9];
  const float* dec_b_h   = (const float*)d_in[10];
  const float* dec_w_out = (const float*)d_in[11];
  const float* dec_b_out = (const float*)d_in[12];

  float* out   = (float*)d_out;
  float* y     = out;                                  // (B,T,8)   131072
  float* x_ae  = out + (size_t)kB * kT * kLat;         // (B,T,3)    49152
  float* x_adv = x_ae + (size_t)kB * kT * kPhys;       // (B,T,3)    49152
  float* y_adv = x_adv + (size_t)kB * kT * kPhys;      // (B,64,8)  131072

  short* wfrag = (short*)d_ws;   // 15 units x 16384 shorts = 491520 B

  split_weights_kernel<<<48, 256, 0, stream>>>(enc_w_h, dec_w_h, wfrag);
  fused_kernel<<<kB, kThreads, 0, stream>>>(
      x, enc_w_in, enc_b_in, enc_b_h, enc_w_out, enc_b_out,
      dec_w_in, dec_b_in, dec_b_h, dec_w_out, dec_b_out,
      wfrag, y, x_ae, x_adv, y_adv);
}